// Round 3
// baseline (346.536 us; speedup 1.0000x reference)
//
#include <hip/hip_runtime.h>
#include <math.h>

// NeighborList: P = N*(N-1)/2 triu pairs, minimum-image distance, cutoff mask.
// out layout (float32, concatenated): [P] pair_i, [P] pair_j, [P*3] pair_diff, [P] pair_dist
//
// Indices are np.triu_indices(N,1) == analytic function of pair index p, so we
// never read idx_i/idx_j from HBM (saves 268 MB of the 1.07 GB traffic).
// Per-pair divides replaced by correctly-rounded reciprocal multiplies:
// rint flips only possible near |delta|~box/2 where the pair is masked under
// either image choice, so outputs stay bit-identical to the reference.

#define NL_CUTOFF 5.0f

typedef float f32x4 __attribute__((ext_vector_type(4)));  // native vec for nontemporal

// i,j from linear triu pair index p: row i starts at off(i) = i*(2N-1-i)/2.
__device__ __forceinline__ void solve_ij(long long p, int N, int& io, int& jo) {
    const double A = (double)(2 * N - 1);
    double disc = A * A - 8.0 * (double)p;
    long long ii = (long long)((A - sqrt(disc)) * 0.5);
    if (ii < 0) ii = 0;
    if (ii > N - 2) ii = N - 2;
    // exact integer fixup (f64 sqrt rounding can be off by 1)
    while (ii > 0 && (ii * (2LL * N - 1 - ii)) >> 1 > p) --ii;
    while (((ii + 1) * (2LL * N - 1 - (ii + 1))) >> 1 <= p) ++ii;
    const long long off = (ii * (2LL * N - 1 - ii)) >> 1;
    io = (int)ii;
    jo = (int)(p - off + ii + 1);
}

struct CellC {
    float r0x, r0y, r0z, rc0;   // row 0 and 1/cell[0][0]
    float r1x, r1y, r1z, rc1;   // row 1 and 1/cell[1][1]
    float r2x, r2y, r2z, rc2;   // row 2 and 1/cell[2][2]
};

__device__ __forceinline__ void pair_compute(
    const float* __restrict__ xyz, const CellC& c,
    int ii, int jj,
    float& oi, float& oj, float& odx, float& ody, float& odz, float& orr)
{
    float dx = __fsub_rn(xyz[3 * ii + 0], xyz[3 * jj + 0]);
    float dy = __fsub_rn(xyz[3 * ii + 1], xyz[3 * jj + 1]);
    float dz = __fsub_rn(xyz[3 * ii + 2], xyz[3 * jj + 2]);

    // z -> y -> x minimum image; reciprocal-mul is rint-safe (see header note)
    float s = rintf(__fmul_rn(dz, c.rc2));
    dx = __fsub_rn(dx, __fmul_rn(s, c.r2x));
    dy = __fsub_rn(dy, __fmul_rn(s, c.r2y));
    dz = __fsub_rn(dz, __fmul_rn(s, c.r2z));

    s = rintf(__fmul_rn(dy, c.rc1));
    dx = __fsub_rn(dx, __fmul_rn(s, c.r1x));
    dy = __fsub_rn(dy, __fmul_rn(s, c.r1y));
    dz = __fsub_rn(dz, __fmul_rn(s, c.r1z));

    s = rintf(__fmul_rn(dx, c.rc0));
    dx = __fsub_rn(dx, __fmul_rn(s, c.r0x));
    dy = __fsub_rn(dy, __fmul_rn(s, c.r0y));
    dz = __fsub_rn(dz, __fmul_rn(s, c.r0z));

    float ss = __fadd_rn(__fadd_rn(__fmul_rn(dx, dx), __fmul_rn(dy, dy)),
                         __fmul_rn(dz, dz));
    float r = __fsqrt_rn(ss);      // correctly rounded: mask boundary bit-exact
    bool m = (r < NL_CUTOFF);

    oi  = m ? (float)ii : -1.0f;
    oj  = m ? (float)jj : -1.0f;
    odx = m ? dx : 0.0f;
    ody = m ? dy : 0.0f;
    odz = m ? dz : 0.0f;
    orr = m ? r  : 0.0f;
}

__device__ __forceinline__ void nt_store4(float* p, float a, float b, float c, float d) {
    f32x4 v = {a, b, c, d};
    __builtin_nontemporal_store(v, (f32x4*)p);
}

__global__ __launch_bounds__(256) void nl_kernel(
    const float* __restrict__ xyz,
    const float* __restrict__ cell,
    float* __restrict__ out,
    long long P, int N)
{
    CellC c;
    c.r0x = cell[0]; c.r0y = cell[1]; c.r0z = cell[2];
    c.r1x = cell[3]; c.r1y = cell[4]; c.r1z = cell[5];
    c.r2x = cell[6]; c.r2y = cell[7]; c.r2z = cell[8];
    c.rc0 = __fdiv_rn(1.0f, c.r0x);
    c.rc1 = __fdiv_rn(1.0f, c.r1y);
    c.rc2 = __fdiv_rn(1.0f, c.r2z);

    float* __restrict__ out_i = out;
    float* __restrict__ out_j = out + P;
    float* __restrict__ out_d = out + 2 * P;   // [P,3] row-major
    float* __restrict__ out_r = out + 5 * P;

    const long long nquad  = P >> 2;
    const long long stride = (long long)gridDim.x * blockDim.x;
    const long long tid0   = (long long)blockIdx.x * blockDim.x + threadIdx.x;

    for (long long q = tid0; q < nquad; q += stride) {
        int i, j;
        solve_ij(q << 2, N, i, j);

        float oia[4], oja[4], ora[4], od[12];
#pragma unroll
        for (int k = 0; k < 4; ++k) {
            pair_compute(xyz, c, i, j,
                         oia[k], oja[k], od[3 * k + 0], od[3 * k + 1],
                         od[3 * k + 2], ora[k]);
            // advance to next triu pair
            if (++j >= N) { ++i; j = i + 1; }
        }

        nt_store4(out_i + (q << 2), oia[0], oia[1], oia[2], oia[3]);
        nt_store4(out_j + (q << 2), oja[0], oja[1], oja[2], oja[3]);
        nt_store4(out_r + (q << 2), ora[0], ora[1], ora[2], ora[3]);
        float* dd = out_d + 12 * q;
        nt_store4(dd + 0, od[0], od[1], od[2],  od[3]);
        nt_store4(dd + 4, od[4], od[5], od[6],  od[7]);
        nt_store4(dd + 8, od[8], od[9], od[10], od[11]);
    }

    // tail (P % 4 != 0 safety; P is divisible by 4 for N=8192)
    for (long long p = (nquad << 2) + tid0; p < P; p += stride) {
        int i, j;
        solve_ij(p, N, i, j);
        float oi, oj, dx, dy, dz, rr;
        pair_compute(xyz, c, i, j, oi, oj, dx, dy, dz, rr);
        out_i[p] = oi;
        out_j[p] = oj;
        out_d[3 * p + 0] = dx;
        out_d[3 * p + 1] = dy;
        out_d[3 * p + 2] = dz;
        out_r[p] = rr;
    }
}

extern "C" void kernel_launch(void* const* d_in, const int* in_sizes, int n_in,
                              void* d_out, int out_size, void* d_ws, size_t ws_size,
                              hipStream_t stream) {
    const float* xyz  = (const float*)d_in[0];
    const float* cell = (const float*)d_in[1];
    float* out = (float*)d_out;

    const int       N = in_sizes[0] / 3;
    const long long P = (long long)in_sizes[2];

    const int block = 256;
    long long nquad = P >> 2;
    long long blocks_needed = (nquad + block - 1) / block;
    int grid = (int)(blocks_needed < 2048 ? (blocks_needed > 0 ? blocks_needed : 1)
                                          : 2048);

    nl_kernel<<<grid, block, 0, stream>>>(xyz, cell, out, P, N);
}

// Round 4
// 161.785 us; speedup vs baseline: 2.1420x; 2.1420x over previous
//
#include <hip/hip_runtime.h>
#include <math.h>

// NeighborList: P = N*(N-1)/2 triu pairs, minimum-image distance, cutoff mask.
// out layout (float32, concatenated): [P] pair_i, [P] pair_j, [P*3] pair_diff, [P] pair_dist
//
// Indices are np.triu_indices(N,1) == analytic function of pair index p, so we
// never read idx_i/idx_j from HBM (saves 268 MB of the 1.07 GB traffic).
// Per-pair divides replaced by correctly-rounded reciprocal multiplies:
// rint flips only possible near |delta|~box/2 where the pair is masked under
// either image choice, so outputs stay bit-identical to the reference.
// R4: plain float4 stores (R3's nontemporal stores regressed 263->347 us;
// write stream is full-line contiguous, L2 write-back already optimal).

#define NL_CUTOFF 5.0f

// i,j from linear triu pair index p: row i starts at off(i) = i*(2N-1-i)/2.
__device__ __forceinline__ void solve_ij(long long p, int N, int& io, int& jo) {
    const double A = (double)(2 * N - 1);
    double disc = A * A - 8.0 * (double)p;
    long long ii = (long long)((A - sqrt(disc)) * 0.5);
    if (ii < 0) ii = 0;
    if (ii > N - 2) ii = N - 2;
    // exact integer fixup (f64 sqrt rounding can be off by 1)
    while (ii > 0 && (ii * (2LL * N - 1 - ii)) >> 1 > p) --ii;
    while (((ii + 1) * (2LL * N - 1 - (ii + 1))) >> 1 <= p) ++ii;
    const long long off = (ii * (2LL * N - 1 - ii)) >> 1;
    io = (int)ii;
    jo = (int)(p - off + ii + 1);
}

struct CellC {
    float r0x, r0y, r0z, rc0;   // row 0 and 1/cell[0][0]
    float r1x, r1y, r1z, rc1;   // row 1 and 1/cell[1][1]
    float r2x, r2y, r2z, rc2;   // row 2 and 1/cell[2][2]
};

__device__ __forceinline__ void pair_compute(
    const float* __restrict__ xyz, const CellC& c,
    int ii, int jj,
    float& oi, float& oj, float& odx, float& ody, float& odz, float& orr)
{
    float dx = __fsub_rn(xyz[3 * ii + 0], xyz[3 * jj + 0]);
    float dy = __fsub_rn(xyz[3 * ii + 1], xyz[3 * jj + 1]);
    float dz = __fsub_rn(xyz[3 * ii + 2], xyz[3 * jj + 2]);

    // z -> y -> x minimum image; reciprocal-mul is rint-safe (see header note)
    float s = rintf(__fmul_rn(dz, c.rc2));
    dx = __fsub_rn(dx, __fmul_rn(s, c.r2x));
    dy = __fsub_rn(dy, __fmul_rn(s, c.r2y));
    dz = __fsub_rn(dz, __fmul_rn(s, c.r2z));

    s = rintf(__fmul_rn(dy, c.rc1));
    dx = __fsub_rn(dx, __fmul_rn(s, c.r1x));
    dy = __fsub_rn(dy, __fmul_rn(s, c.r1y));
    dz = __fsub_rn(dz, __fmul_rn(s, c.r1z));

    s = rintf(__fmul_rn(dx, c.rc0));
    dx = __fsub_rn(dx, __fmul_rn(s, c.r0x));
    dy = __fsub_rn(dy, __fmul_rn(s, c.r0y));
    dz = __fsub_rn(dz, __fmul_rn(s, c.r0z));

    float ss = __fadd_rn(__fadd_rn(__fmul_rn(dx, dx), __fmul_rn(dy, dy)),
                         __fmul_rn(dz, dz));
    float r = __fsqrt_rn(ss);      // correctly rounded: mask boundary bit-exact
    bool m = (r < NL_CUTOFF);

    oi  = m ? (float)ii : -1.0f;
    oj  = m ? (float)jj : -1.0f;
    odx = m ? dx : 0.0f;
    ody = m ? dy : 0.0f;
    odz = m ? dz : 0.0f;
    orr = m ? r  : 0.0f;
}

__global__ __launch_bounds__(256) void nl_kernel(
    const float* __restrict__ xyz,
    const float* __restrict__ cell,
    float* __restrict__ out,
    long long P, int N)
{
    CellC c;
    c.r0x = cell[0]; c.r0y = cell[1]; c.r0z = cell[2];
    c.r1x = cell[3]; c.r1y = cell[4]; c.r1z = cell[5];
    c.r2x = cell[6]; c.r2y = cell[7]; c.r2z = cell[8];
    c.rc0 = __fdiv_rn(1.0f, c.r0x);
    c.rc1 = __fdiv_rn(1.0f, c.r1y);
    c.rc2 = __fdiv_rn(1.0f, c.r2z);

    float* __restrict__ out_i = out;
    float* __restrict__ out_j = out + P;
    float* __restrict__ out_d = out + 2 * P;   // [P,3] row-major
    float* __restrict__ out_r = out + 5 * P;

    const long long nquad  = P >> 2;
    const long long stride = (long long)gridDim.x * blockDim.x;
    const long long tid0   = (long long)blockIdx.x * blockDim.x + threadIdx.x;

    for (long long q = tid0; q < nquad; q += stride) {
        int i, j;
        solve_ij(q << 2, N, i, j);

        float oia[4], oja[4], ora[4], od[12];
#pragma unroll
        for (int k = 0; k < 4; ++k) {
            pair_compute(xyz, c, i, j,
                         oia[k], oja[k], od[3 * k + 0], od[3 * k + 1],
                         od[3 * k + 2], ora[k]);
            // advance to next triu pair
            if (++j >= N) { ++i; j = i + 1; }
        }

        ((float4*)out_i)[q] = make_float4(oia[0], oia[1], oia[2], oia[3]);
        ((float4*)out_j)[q] = make_float4(oja[0], oja[1], oja[2], oja[3]);
        ((float4*)out_r)[q] = make_float4(ora[0], ora[1], ora[2], ora[3]);
        float4* dd = (float4*)(out_d + 12 * q);
        dd[0] = make_float4(od[0], od[1],  od[2],  od[3]);
        dd[1] = make_float4(od[4], od[5],  od[6],  od[7]);
        dd[2] = make_float4(od[8], od[9],  od[10], od[11]);
    }

    // tail (P % 4 != 0 safety; P is divisible by 4 for N=8192)
    for (long long p = (nquad << 2) + tid0; p < P; p += stride) {
        int i, j;
        solve_ij(p, N, i, j);
        float oi, oj, dx, dy, dz, rr;
        pair_compute(xyz, c, i, j, oi, oj, dx, dy, dz, rr);
        out_i[p] = oi;
        out_j[p] = oj;
        out_d[3 * p + 0] = dx;
        out_d[3 * p + 1] = dy;
        out_d[3 * p + 2] = dz;
        out_r[p] = rr;
    }
}

extern "C" void kernel_launch(void* const* d_in, const int* in_sizes, int n_in,
                              void* d_out, int out_size, void* d_ws, size_t ws_size,
                              hipStream_t stream) {
    const float* xyz  = (const float*)d_in[0];
    const float* cell = (const float*)d_in[1];
    float* out = (float*)d_out;

    const int       N = in_sizes[0] / 3;
    const long long P = (long long)in_sizes[2];

    const int block = 256;
    long long nquad = P >> 2;
    long long blocks_needed = (nquad + block - 1) / block;
    int grid = (int)(blocks_needed < 2048 ? (blocks_needed > 0 ? blocks_needed : 1)
                                          : 2048);

    nl_kernel<<<grid, block, 0, stream>>>(xyz, cell, out, P, N);
}